// Round 10
// baseline (145.484 us; speedup 1.0000x reference)
//
#include <hip/hip_runtime.h>
#include <hip/hip_bf16.h>

#define NN 8192
#define IN_F 256
#define OF 128

typedef float  f32x4   __attribute__((ext_vector_type(4)));
typedef short  short4v __attribute__((ext_vector_type(4)));
typedef short  short8v __attribute__((ext_vector_type(8)));
typedef int    int4v   __attribute__((ext_vector_type(4)));

__device__ __forceinline__ unsigned short bf16_bits(float x) {
    __bf16 b = (__bf16)x;
    return __builtin_bit_cast(unsigned short, b);
}

__device__ __forceinline__ f32x4 mfma16(short4v a, short4v b, f32x4 c) {
#if __has_builtin(__builtin_amdgcn_mfma_f32_16x16x16bf16_1k)
    return __builtin_amdgcn_mfma_f32_16x16x16bf16_1k(a, b, c, 0, 0, 0);
#else
    asm("v_mfma_f32_16x16x16_bf16 %0, %1, %2, %0" : "+v"(c) : "v"(a), "v"(b));
    return c;
#endif
}

// ---------------------------------------------------------------------------
// Kernel A: h = X @ W (f32, LDS-staged W).  Emits HtB in MFMA-B-fragment
// order (verified R3+):  for h[j][f]:
//   kt=j>>4, g=(j>>2)&3, e=j&3, np=f>>5, o=(f>>4)&1, c=f&15
//   short index = ((kt*4+np)*64 + g*16 + c)*8 + o*4 + e
// Also f_src = h.a[:OF], f_dst = h.a[OF:].
// ---------------------------------------------------------------------------
__global__ __launch_bounds__(256) void gat_prep(
    const float* __restrict__ X, const float* __restrict__ W,
    const float* __restrict__ a, unsigned short* __restrict__ HtB,
    float* __restrict__ f_src, float* __restrict__ f_dst)
{
    __shared__ float Wlds[IN_F * OF];   // 128 KiB
    __shared__ float red_s[32][8];
    __shared__ float red_d[32][8];

    const int t = threadIdx.x;
    {
        const f32x4* Wv = (const f32x4*)W;
        f32x4*       Wl = (f32x4*)Wlds;
        #pragma unroll
        for (int c = 0; c < 32; ++c) Wl[c * 256 + t] = Wv[c * 256 + t];
    }
    __syncthreads();

    const int row = t & 31;
    const int sub = t >> 5;
    const int i   = blockIdx.x * 32 + row;

    f32x4 acc[4] = {};
    const float* xrow = X + (size_t)i * IN_F;

    #pragma unroll 4
    for (int kk = 0; kk < IN_F; kk += 4) {
        f32x4 xv = *(const f32x4*)(xrow + kk);
        #pragma unroll
        for (int e = 0; e < 4; ++e) {
            const f32x4* wr = (const f32x4*)(Wlds + (kk + e) * OF + sub * 16);
            float xs = xv[e];
            #pragma unroll
            for (int c4 = 0; c4 < 4; ++c4) acc[c4] += xs * wr[c4];
        }
    }

    const int kt = i >> 4;
    const int gq = (i >> 2) & 3;
    const int eq = i & 3;
    const int np = sub >> 1;
    const int oo = sub & 1;

    float ps = 0.f, pd = 0.f;
    #pragma unroll
    for (int c4 = 0; c4 < 4; ++c4) {
        #pragma unroll
        for (int e = 0; e < 4; ++e) {
            float v = acc[c4][e];
            int   c = c4 * 4 + e;
            ps += v * a[sub * 16 + c];
            pd += v * a[OF + sub * 16 + c];
            HtB[(size_t)(((kt * 4 + np) * 64) + gq * 16 + c) * 8 + oo * 4 + eq]
                = bf16_bits(v);
        }
    }
    red_s[row][sub] = ps;
    red_d[row][sub] = pd;
    __syncthreads();
    if (t < 32) {
        float s = 0.f;
        #pragma unroll
        for (int s8 = 0; s8 < 8; ++s8) s += red_s[t][s8];
        f_src[blockIdx.x * 32 + t] = s;
    } else if (t < 64) {
        const int r2 = t - 32;
        float s = 0.f;
        #pragma unroll
        for (int s8 = 0; s8 < 8; ++s8) s += red_d[r2][s8];
        f_dst[blockIdx.x * 32 + r2] = s;
    }
}

// ---------------------------------------------------------------------------
// Kernel B v10: flash-GAT, latency-AMORTIZED (kt-batch = 4).
// 512 blocks x 512 threads (8 waves), 16 rows/block; wave w owns kt =
// ss*32 + w*4 + {0..3};  16 iterations of:
//   [issue 4 adj int4 + 4 f_dst f32x4 + 16 B-fragment loads]
//   sched_barrier(0)          <- loads may not sink into compute
//   [4x (exp block + 8 MFMA)]
// One L2/HBM latency exposure amortizes over 4 kt + 32 MFMAs, and the
// counted per-register waits let later loads pipeline behind the first.
// No LDS / no barriers in the loop (waves independent).  blockIdx-rotated
// superstep start decorrelates L2 channel convoys.
// ---------------------------------------------------------------------------
__global__ __launch_bounds__(512, 3) void gat_flash(
    const int* __restrict__ adj, const short8v* __restrict__ htv,
    const float* __restrict__ f_src, const float* __restrict__ f_dst,
    float* __restrict__ out)
{
    __shared__ __align__(16) float red[8][16][OF];   // 64 KiB (epilogue only)
    __shared__ float rden[8][16];

    const int tid  = threadIdx.x;
    const int w    = tid >> 6;
    const int lane = tid & 63;
    const int r    = lane & 15;
    const int g    = lane >> 4;
    const int rowbase = blockIdx.x * 16;
    const int row  = rowbase + r;
    const int start = blockIdx.x & 15;

    const float fsrc_r = f_src[row];
    const int* aptr = adj + (size_t)row * NN + g * 4;

    f32x4 acc[8] = {};
    float psum = 0.f;

    for (int it = 0; it < 16; ++it) {
        const int ktb = ((it + start) & 15) * 32 + w * 4;   // 4 consecutive kt

        int4v   av[4];
        f32x4   fv[4];
        short8v bv[16];

        // ---- load block: slowest stream (adj, HBM/L3) first ----
        #pragma unroll
        for (int j = 0; j < 4; ++j)
            av[j] = *(const int4v*)(aptr + (ktb + j) * 16);
        #pragma unroll
        for (int j = 0; j < 4; ++j)
            fv[j] = *(const f32x4*)(f_dst + (ktb + j) * 16 + g * 4);
        #pragma unroll
        for (int j = 0; j < 4; ++j)
            #pragma unroll
            for (int q = 0; q < 4; ++q)
                bv[j * 4 + q] = htv[(size_t)((ktb + j) * 4 + q) * 64 + lane];

        __builtin_amdgcn_sched_barrier(0);   // pin: no load sinks past here

        // ---- compute block ----
        #pragma unroll
        for (int j = 0; j < 4; ++j) {
            float p[4];
            #pragma unroll
            for (int e = 0; e < 4; ++e) {
                float s = fsrc_r + fv[j][e];
                s = s > 0.f ? s : 0.2f * s;          // leaky_relu
                p[e] = (av[j][e] != 0) ? __expf(s) : 0.f;
            }
            psum += (p[0] + p[1]) + (p[2] + p[3]);
            const short4v af = { (short)bf16_bits(p[0]), (short)bf16_bits(p[1]),
                                 (short)bf16_bits(p[2]), (short)bf16_bits(p[3]) };

            const short8v b0 = bv[j * 4 + 0];
            const short8v b1 = bv[j * 4 + 1];
            const short8v b2 = bv[j * 4 + 2];
            const short8v b3 = bv[j * 4 + 3];
            acc[0] = mfma16(af, __builtin_shufflevector(b0, b0, 0, 1, 2, 3), acc[0]);
            acc[1] = mfma16(af, __builtin_shufflevector(b0, b0, 4, 5, 6, 7), acc[1]);
            acc[2] = mfma16(af, __builtin_shufflevector(b1, b1, 0, 1, 2, 3), acc[2]);
            acc[3] = mfma16(af, __builtin_shufflevector(b1, b1, 4, 5, 6, 7), acc[3]);
            acc[4] = mfma16(af, __builtin_shufflevector(b2, b2, 0, 1, 2, 3), acc[4]);
            acc[5] = mfma16(af, __builtin_shufflevector(b2, b2, 4, 5, 6, 7), acc[5]);
            acc[6] = mfma16(af, __builtin_shufflevector(b3, b3, 0, 1, 2, 3), acc[6]);
            acc[7] = mfma16(af, __builtin_shufflevector(b3, b3, 4, 5, 6, 7), acc[7]);
        }
    }

    // denom: reduce psum over the 4 g-groups
    psum += __shfl_xor(psum, 16, 64);
    psum += __shfl_xor(psum, 32, 64);
    if (lane < 16) rden[w][lane] = psum;

    #pragma unroll
    for (int nf = 0; nf < 8; ++nf)
        #pragma unroll
        for (int q = 0; q < 4; ++q)
            red[w][g * 4 + q][nf * 16 + r] = acc[nf][q];
    __syncthreads();

    // epilogue: 512 threads x 1 f32x4 = 16x128 tile
    const int orow = tid >> 5;     // 0..15
    const int cg   = tid & 31;     // 4-col group
    f32x4 v = {};
    float den = 0.f;
    #pragma unroll
    for (int ww = 0; ww < 8; ++ww) {
        v   += *(const f32x4*)&red[ww][orow][cg * 4];
        den += rden[ww][orow];
    }
    const float inv = 1.0f / den;
    f32x4 o = v * inv;
    #pragma unroll
    for (int e = 0; e < 4; ++e) o[e] = fmaxf(o[e], 0.f);
    *(f32x4*)(out + (size_t)(rowbase + orow) * OF + cg * 4) = o;
}

extern "C" void kernel_launch(void* const* d_in, const int* in_sizes, int n_in,
                              void* d_out, int out_size, void* d_ws, size_t ws_size,
                              hipStream_t stream) {
    const float* X   = (const float*)d_in[0];
    const int*   adj = (const int*)d_in[1];
    const float* W   = (const float*)d_in[2];
    const float* a   = (const float*)d_in[3];
    float* out = (float*)d_out;

    char* ws = (char*)d_ws;
    unsigned short* HtB   = (unsigned short*)ws;                 // 2 MiB
    float*          f_src = (float*)(ws + 2097152);              // 32 KiB
    float*          f_dst = (float*)(ws + 2097152 + 32768);      // 32 KiB

    gat_prep<<<NN / 32, 256, 0, stream>>>(X, W, a, HtB, f_src, f_dst);
    gat_flash<<<NN / 16, 512, 0, stream>>>(adj, (const short8v*)HtB,
                                           f_src, f_dst, out);
}

// Round 11
// 129.830 us; speedup vs baseline: 1.1206x; 1.1206x over previous
//
#include <hip/hip_runtime.h>
#include <hip/hip_bf16.h>

#define NN 8192
#define IN_F 256
#define OF 128
#define NT 512            // NN/16 k-tiles

typedef float  f32x4   __attribute__((ext_vector_type(4)));
typedef short  short4v __attribute__((ext_vector_type(4)));
typedef short  short8v __attribute__((ext_vector_type(8)));
typedef int    int4v   __attribute__((ext_vector_type(4)));

__device__ __forceinline__ unsigned short bf16_bits(float x) {
    __bf16 b = (__bf16)x;
    return __builtin_bit_cast(unsigned short, b);
}

__device__ __forceinline__ f32x4 mfma16(short4v a, short4v b, f32x4 c) {
#if __has_builtin(__builtin_amdgcn_mfma_f32_16x16x16bf16_1k)
    return __builtin_amdgcn_mfma_f32_16x16x16bf16_1k(a, b, c, 0, 0, 0);
#else
    asm("v_mfma_f32_16x16x16_bf16 %0, %1, %2, %0" : "+v"(c) : "v"(a), "v"(b));
    return c;
#endif
}

// ---------------------------------------------------------------------------
// Kernel A: h = X @ W (f32, LDS-staged W).  Emits HtB in MFMA-B-fragment
// order (verified R3+):  for h[j][f]:
//   kt=j>>4, g=(j>>2)&3, e=j&3, np=f>>5, o=(f>>4)&1, c=f&15
//   short index = ((kt*4+np)*64 + g*16 + c)*8 + o*4 + e
// Also f_src = h.a[:OF], f_dst = h.a[OF:].
// ---------------------------------------------------------------------------
__global__ __launch_bounds__(256) void gat_prep(
    const float* __restrict__ X, const float* __restrict__ W,
    const float* __restrict__ a, unsigned short* __restrict__ HtB,
    float* __restrict__ f_src, float* __restrict__ f_dst)
{
    __shared__ float Wlds[IN_F * OF];   // 128 KiB
    __shared__ float red_s[32][8];
    __shared__ float red_d[32][8];

    const int t = threadIdx.x;
    {
        const f32x4* Wv = (const f32x4*)W;
        f32x4*       Wl = (f32x4*)Wlds;
        #pragma unroll
        for (int c = 0; c < 32; ++c) Wl[c * 256 + t] = Wv[c * 256 + t];
    }
    __syncthreads();

    const int row = t & 31;
    const int sub = t >> 5;
    const int i   = blockIdx.x * 32 + row;

    f32x4 acc[4] = {};
    const float* xrow = X + (size_t)i * IN_F;

    #pragma unroll 4
    for (int kk = 0; kk < IN_F; kk += 4) {
        f32x4 xv = *(const f32x4*)(xrow + kk);
        #pragma unroll
        for (int e = 0; e < 4; ++e) {
            const f32x4* wr = (const f32x4*)(Wlds + (kk + e) * OF + sub * 16);
            float xs = xv[e];
            #pragma unroll
            for (int c4 = 0; c4 < 4; ++c4) acc[c4] += xs * wr[c4];
        }
    }

    const int kt = i >> 4;
    const int gq = (i >> 2) & 3;
    const int eq = i & 3;
    const int np = sub >> 1;
    const int oo = sub & 1;

    float ps = 0.f, pd = 0.f;
    #pragma unroll
    for (int c4 = 0; c4 < 4; ++c4) {
        #pragma unroll
        for (int e = 0; e < 4; ++e) {
            float v = acc[c4][e];
            int   c = c4 * 4 + e;
            ps += v * a[sub * 16 + c];
            pd += v * a[OF + sub * 16 + c];
            HtB[(size_t)(((kt * 4 + np) * 64) + gq * 16 + c) * 8 + oo * 4 + eq]
                = bf16_bits(v);
        }
    }
    red_s[row][sub] = ps;
    red_d[row][sub] = pd;
    __syncthreads();
    if (t < 32) {
        float s = 0.f;
        #pragma unroll
        for (int s8 = 0; s8 < 8; ++s8) s += red_s[t][s8];
        f_src[blockIdx.x * 32 + t] = s;
    } else if (t < 64) {
        const int r2 = t - 32;
        float s = 0.f;
        #pragma unroll
        for (int s8 = 0; s8 < 8; ++s8) s += red_d[r2][s8];
        f_dst[blockIdx.x * 32 + r2] = s;
    }
}

// ---------------------------------------------------------------------------
// Kernel B v11: FAT-iteration fused flash-GAT.
// Grid = 128 M-blocks x 2 k-splits = 256 blocks (exactly 1/CU) x 512 threads.
// Block = 64 rows (4 row-tiles rt).  Wave w owns kt-chunk [ks*256 + w*32, +32):
// 32 iterations, each: 4 adj int4 loads (64 full lines) + 1 f_dst + 4 B-frag
// 1KB loads + 16 exps + 32 MFMAs -> one latency exposure amortized over 4x
// the MFMA work of the old thin loop.  adj is read exactly once across the
// grid (k-ranges disjoint); per-CU adj slice = 1 MB -> ~42 us HBM floor.
// Partial acc + partial rowsums written f32 to ws; finish sums 2 slices.
// ---------------------------------------------------------------------------
__global__ __launch_bounds__(512, 2) void gat_fat(
    const int* __restrict__ adj, const short8v* __restrict__ htv,
    const float* __restrict__ f_src, const float* __restrict__ f_dst,
    float* __restrict__ part, float* __restrict__ rsPart)
{
    __shared__ float slab[4][64][OF];   // 128 KiB
    __shared__ float rsum[8][64];       // 2 KiB

    const int tid  = threadIdx.x;
    const int w    = tid >> 6;
    const int lane = tid & 63;
    const int r    = lane & 15;
    const int g    = lane >> 4;
    const int ms   = blockIdx.x >> 1;
    const int ks   = blockIdx.x & 1;
    const int rowbase = ms * 64;
    const int ktbase  = ks * 256 + w * 32;

    float fsrc[4];
    const int* ap[4];
    #pragma unroll
    for (int rt = 0; rt < 4; ++rt) {
        fsrc[rt] = f_src[rowbase + rt * 16 + r];
        ap[rt]   = adj + (size_t)(rowbase + rt * 16 + r) * NN + g * 4;
    }

    f32x4 acc[4][8] = {};
    float psum[4] = {};

    // depth-1 adj prefetch
    int4v avc[4];
    #pragma unroll
    for (int rt = 0; rt < 4; ++rt)
        avc[rt] = *(const int4v*)(ap[rt] + ktbase * 16);

    for (int it = 0; it < 32; ++it) {
        const int kt = ktbase + it;

        // next iteration's adj (slowest stream) first
        int4v avn[4];
        const int ktn = (it + 1 < 32) ? kt + 1 : kt;
        #pragma unroll
        for (int rt = 0; rt < 4; ++rt)
            avn[rt] = *(const int4v*)(ap[rt] + ktn * 16);

        const f32x4 fd = *(const f32x4*)(f_dst + kt * 16 + g * 4);

        short8v bv[4];
        #pragma unroll
        for (int q = 0; q < 4; ++q)
            bv[q] = htv[(size_t)(kt * 4 + q) * 64 + lane];

        __builtin_amdgcn_sched_barrier(0);   // loads may not sink into compute

        short4v af[4];
        #pragma unroll
        for (int rt = 0; rt < 4; ++rt) {
            float p[4];
            #pragma unroll
            for (int e = 0; e < 4; ++e) {
                float s = fsrc[rt] + fd[e];
                s = s > 0.f ? s : 0.2f * s;          // leaky_relu
                p[e] = (avc[rt][e] != 0) ? __expf(s) : 0.f;
            }
            psum[rt] += (p[0] + p[1]) + (p[2] + p[3]);
            af[rt] = { (short)bf16_bits(p[0]), (short)bf16_bits(p[1]),
                       (short)bf16_bits(p[2]), (short)bf16_bits(p[3]) };
        }

        #pragma unroll
        for (int q = 0; q < 4; ++q) {
            const short4v lo = __builtin_shufflevector(bv[q], bv[q], 0, 1, 2, 3);
            const short4v hi = __builtin_shufflevector(bv[q], bv[q], 4, 5, 6, 7);
            #pragma unroll
            for (int rt = 0; rt < 4; ++rt) {
                acc[rt][2 * q]     = mfma16(af[rt], lo, acc[rt][2 * q]);
                acc[rt][2 * q + 1] = mfma16(af[rt], hi, acc[rt][2 * q + 1]);
            }
        }

        #pragma unroll
        for (int rt = 0; rt < 4; ++rt) avc[rt] = avn[rt];
    }

    // rowsum partials: reduce over the 4 g-groups
    #pragma unroll
    for (int rt = 0; rt < 4; ++rt) {
        psum[rt] += __shfl_xor(psum[rt], 16, 64);
        psum[rt] += __shfl_xor(psum[rt], 32, 64);
    }
    if (lane < 16) {
        #pragma unroll
        for (int rt = 0; rt < 4; ++rt) rsum[w][rt * 16 + lane] = psum[rt];
    }

    // cross-wave acc reduction: waves 4-7 write slabs, 0-3 add
    if (w >= 4) {
        #pragma unroll
        for (int rt = 0; rt < 4; ++rt)
            #pragma unroll
            for (int nf = 0; nf < 8; ++nf)
                #pragma unroll
                for (int q = 0; q < 4; ++q)
                    slab[w - 4][rt * 16 + 4 * g + q][nf * 16 + r] = acc[rt][nf][q];
    }
    __syncthreads();
    if (w < 4) {
        #pragma unroll
        for (int rt = 0; rt < 4; ++rt)
            #pragma unroll
            for (int nf = 0; nf < 8; ++nf)
                #pragma unroll
                for (int q = 0; q < 4; ++q)
                    slab[w][rt * 16 + 4 * g + q][nf * 16 + r] += acc[rt][nf][q];
    }
    __syncthreads();

    // write 64x128 f32 partial tile + 64 rowsum partials
    float* pb = part + ((size_t)ks * NN + rowbase) * OF;
    #pragma unroll
    for (int c = 0; c < 4; ++c) {
        const int tg  = c * 512 + tid;
        const int row = tg >> 5;
        const int cg  = tg & 31;
        f32x4 v = *(const f32x4*)&slab[0][row][cg * 4];
        v += *(const f32x4*)&slab[1][row][cg * 4];
        v += *(const f32x4*)&slab[2][row][cg * 4];
        v += *(const f32x4*)&slab[3][row][cg * 4];
        *(f32x4*)(pb + (size_t)row * OF + cg * 4) = v;
    }
    if (tid < 64) {
        float s = 0.f;
        #pragma unroll
        for (int w8 = 0; w8 < 8; ++w8) s += rsum[w8][tid];
        rsPart[ks * NN + rowbase + tid] = s;
    }
}

// ---------------------------------------------------------------------------
// Finish: out = relu( (part0+part1) / (rs0+rs1) ).  512 blocks x 512 threads.
// ---------------------------------------------------------------------------
__global__ __launch_bounds__(512) void gat_finish(
    const float* __restrict__ part, const float* __restrict__ rsPart,
    float* __restrict__ out)
{
    const int tg  = blockIdx.x * 512 + threadIdx.x;   // f32x4 index
    const int row = tg >> 5;

    f32x4 v = *(const f32x4*)(part + (size_t)tg * 4);
    v += *(const f32x4*)(part + (size_t)NN * OF + (size_t)tg * 4);

    const float den = rsPart[row] + rsPart[NN + row];
    const float inv = 1.0f / den;
    f32x4 o = v * inv;
    #pragma unroll
    for (int e = 0; e < 4; ++e) o[e] = fmaxf(o[e], 0.f);
    *(f32x4*)(out + (size_t)tg * 4) = o;
}

extern "C" void kernel_launch(void* const* d_in, const int* in_sizes, int n_in,
                              void* d_out, int out_size, void* d_ws, size_t ws_size,
                              hipStream_t stream) {
    const float* X   = (const float*)d_in[0];
    const int*   adj = (const int*)d_in[1];
    const float* W   = (const float*)d_in[2];
    const float* a   = (const float*)d_in[3];
    float* out = (float*)d_out;

    char* ws = (char*)d_ws;
    unsigned short* HtB    = (unsigned short*)ws;                  // 2 MiB
    float*          f_src  = (float*)(ws + 2097152);               // 32 KiB
    float*          f_dst  = (float*)(ws + 2097152 + 32768);       // 32 KiB
    float*          rsPart = (float*)(ws + 2097152 + 65536);       // 64 KiB
    float*          part   = (float*)(ws + 2097152 + 131072);      // 8 MiB

    gat_prep<<<NN / 32, 256, 0, stream>>>(X, W, a, HtB, f_src, f_dst);
    gat_fat<<<256, 512, 0, stream>>>(adj, (const short8v*)HtB,
                                     f_src, f_dst, part, rsPart);
    gat_finish<<<512, 512, 0, stream>>>(part, rsPart, out);
}